// Round 9
// baseline (37.776 us; speedup 1.0000x reference)
//
#include <hip/hip_runtime.h>
#include <math.h>

#define BLKSZ 160
#define NWT   64
#define WTLEN 512
#define FPB   16      // frames per main block
#define SPB   2560    // samples per main block (16*160)

// ReduceWindowRewriter(base_length=16) level sizes for T=960000
#define NB0   60000   // T/16
#define NB1   3750    // NB0/16
#define NB2   235     // ceil(NB1/16)
#define NB2P  240
#define NB3   15      // < 16 -> naive sequential top scan

#define LEAFB 235     // leaf-tree blocks (4096 samples each)
#define WTSB  128     // wts_eff blocks (32768/256)
#define SMB   24      // softmax blocks (ceil(6000/256))

// f32 increment exactly as the reference: (pitch / 16000) * 512
static __device__ __forceinline__ float inc32_of(float p) {
    return (p / 16000.0f) * 512.0f;
}

// K_A: leaf tree + wts_eff + softmax->wT, partitioned by blockIdx
__global__ __launch_bounds__(256) void k_front(
    const float* __restrict__ pitch, const float* __restrict__ wts,
    const float* __restrict__ att,
    float* __restrict__ bs1, float* __restrict__ bs2,
    float* __restrict__ wts_eff, float* __restrict__ wT,
    int T, int frames)
{
    int t = threadIdx.x;
    int bid = blockIdx.x;

    if (bid < LEAFB) {                            // ---- leaf tree ----
        __shared__ float b0[256];
        __shared__ float b1[16];
        size_t s0 = (size_t)bid * 4096;
        int nsamp = min(4096, T - (int)s0);
        int nb0 = nsamp >> 4;                     // 256 or 96
        if (t < nb0) {                            // bs0: seq 16-chain of incs
            const float4* p4 = (const float4*)(pitch + s0 + (size_t)t * 16);
            float acc = 0.f;
            #pragma unroll
            for (int i = 0; i < 4; ++i) {
                float4 v = p4[i];
                acc = acc + inc32_of(v.x);
                acc = acc + inc32_of(v.y);
                acc = acc + inc32_of(v.z);
                acc = acc + inc32_of(v.w);
            }
            b0[t] = acc;
        }
        __syncthreads();
        int nb1 = nb0 >> 4;                       // 16 or 6
        if (t < nb1) {                            // bs1: seq 16-chain of bs0
            float acc = b0[t * 16];
            for (int j = 1; j < 16; ++j) acc = acc + b0[t * 16 + j];
            b1[t] = acc;
            bs1[bid * 16 + t] = acc;
        }
        __syncthreads();
        if (t == 0) {                             // bs2: seq chain
            float acc = b1[0];
            for (int j = 1; j < nb1; ++j) acc = acc + b1[j];
            bs2[bid] = acc;
        }
        return;
    }
    if (bid < LEAFB + WTSB) {                     // ---- wts_eff ----
        int i = (bid - LEAFB) * 256 + t;
        if (i < NWT * WTLEN) {
            float v = wts[i];
            if ((i >> 9) >= 4) v = tanhf(v);
            wts_eff[i] = v;
        }
        return;
    }
    // ---- softmax: one thread per frame; weights to wT[b][w][k] ----
    int f = (bid - LEAFB - WTSB) * 256 + t;
    if (f >= frames) return;
    float m = att[f];
    for (int w = 1; w < NWT; ++w) m = fmaxf(m, att[(size_t)w * frames + f]);
    float s = 0.f;
    for (int w = 0; w < NWT; ++w) s += expf(att[(size_t)w * frames + f] - m);
    float* dst = wT + (size_t)(f >> 4) * (NWT * FPB) + (f & 15);
    for (int w = 0; w < NWT; ++w)
        dst[w * FPB] = expf(att[(size_t)w * frames + f] - m) / s;
}

// K_B: mid levels: bs2 -> bs3 -> S4 -> S3  (tiny single block)
__global__ __launch_bounds__(256) void k_s3(const float* __restrict__ bs2,
                                            float* __restrict__ S3)
{
    __shared__ float bs2L[NB2P];
    __shared__ float bs3L[NB3];
    __shared__ float S4L[NB3];
    int t = threadIdx.x;
    if (t < NB2P) bs2L[t] = (t < NB2) ? bs2[t] : 0.f;
    __syncthreads();
    if (t < NB3) {                                // bs3: seq 16-chain of bs2
        float acc = bs2L[t * 16];
        for (int j = 1; j < 16; ++j) acc = acc + bs2L[t * 16 + j];
        bs3L[t] = acc;
    }
    __syncthreads();
    if (t == 0) {                                 // S4: naive seq scan (15 < 16)
        float acc = 0.f;
        for (int i = 0; i < NB3; ++i) { acc = acc + bs3L[i]; S4L[i] = acc; }
    }
    __syncthreads();
    if (t < NB2) {                                // S3 = inner3 + off4
        int r = t >> 4, i = t & 15;
        float acc = bs2L[r * 16];
        for (int k = 1; k <= i; ++k) acc = acc + bs2L[r * 16 + k];
        S3[t] = r ? (acc + S4L[r - 1]) : acc;
    }
}

// K_C: mixrow (SGPR weights) -> local S2 window -> prefixes -> lerp -> amp
__global__ __launch_bounds__(512) void k_main(
    const float* __restrict__ pitch, const float* __restrict__ amp,
    const float* __restrict__ wts_eff, const float* __restrict__ wT,
    const float* __restrict__ bs1, const float* __restrict__ S3,
    float* __restrict__ out, int frames)
{
    __shared__ float mixrow[FPB][WTLEN];    // 32 KB
    __shared__ float pr[SPB];               // 10 KB: inc -> within-16 prefix
    __shared__ float roffL[SPB / 16];       // 160
    __shared__ float S2w[11];               // S2[10b-2 .. 10b+8]
    __shared__ float bs1w[32];              // bs1 rows rlo, rlo+1
    __shared__ float S3w[2];                // S3[rlo-1], S3[rlo]
    __shared__ float bs1prevL;

    int tid = threadIdx.x;
    int b = blockIdx.x;
    size_t base = (size_t)b * SPB;
    int j0 = 10 * b - 2;
    int rlo = max(j0, 0) >> 4;

    // stage incs (regs + LDS)
    float increg[SPB / 512];
    #pragma unroll
    for (int i = 0; i < SPB / 512; ++i) {
        increg[i] = inc32_of(pitch[base + i * 512 + tid]);
        pr[i * 512 + tid] = increg[i];
    }
    // stage bs1/S3 windows
    if (tid >= 448 && tid < 480) {
        int idx = tid - 448;
        int g = rlo * 16 + idx;
        bs1w[idx] = (g < NB1) ? bs1[g] : 0.f;
    }
    if (tid == 440) bs1prevL = (b > 0) ? bs1[10 * b - 1] : 0.f;
    if (tid == 441) S3w[0] = (rlo >= 1) ? S3[rlo - 1] : 0.f;
    if (tid == 442) S3w[1] = (rlo < NB2) ? S3[rlo] : 0.f;
    __syncthreads();

    // local S2 window: S2[j] = inner2(j) + S3[r-1]  (bit-exact chains)
    if (tid < 11) {
        int j = j0 + tid;
        float v = 0.f;
        if (j >= 0) {
            int r = j >> 4, p = j & 15;
            int o = (r - rlo) * 16;
            float acc = bs1w[o];
            for (int q = 1; q <= p; ++q) acc = acc + bs1w[o + q];
            v = r ? (acc + S3w[r - rlo]) : acc;
        }
        S2w[tid] = v;
    }
    // within-16 inclusive prefixes, in place
    if (tid >= 64 && tid < 64 + SPB / 16) {
        int row = tid - 64;
        int bofs = row * 16;
        float acc = pr[bofs];
        for (int j = 1; j < 16; ++j) { acc = acc + pr[bofs + j]; pr[bofs + j] = acc; }
    }

    // mixrow: uniform-address weight loads (SGPR) + per-thread wts_eff column
    {
        const float* __restrict__ wTb = wT + (size_t)b * (NWT * FPB);
        float acc[FPB];
        #pragma unroll
        for (int k = 0; k < FPB; ++k) acc[k] = 0.f;
        for (int w = 0; w < NWT; ++w) {
            float v = wts_eff[w * WTLEN + tid];
            const float4* wp = (const float4*)(wTb + w * FPB);
            float4 A0 = wp[0], A1 = wp[1], A2 = wp[2], A3 = wp[3];
            acc[0]  += A0.x * v;  acc[1]  += A0.y * v;
            acc[2]  += A0.z * v;  acc[3]  += A0.w * v;
            acc[4]  += A1.x * v;  acc[5]  += A1.y * v;
            acc[6]  += A1.z * v;  acc[7]  += A1.w * v;
            acc[8]  += A2.x * v;  acc[9]  += A2.y * v;
            acc[10] += A2.z * v;  acc[11] += A2.w * v;
            acc[12] += A3.x * v;  acc[13] += A3.y * v;
            acc[14] += A3.z * v;  acc[15] += A3.w * v;
        }
        #pragma unroll
        for (int k = 0; k < FPB; ++k) mixrow[k][tid] = acc[k];
    }
    __syncthreads();

    // roffL[t] = S1[160b + t - 1], recomputed locally (identical chains)
    if (tid < SPB / 16) {
        float v;
        if (tid == 0) {
            v = (b == 0) ? 0.f : (bs1prevL + S2w[0]);
        } else {
            int lr = (tid - 1) >> 4;
            int p  = (tid - 1) & 15;
            float acc = pr[(lr * 16) * 16 + 15];
            for (int q = 1; q <= p; ++q) acc = acc + pr[(lr * 16 + q) * 16 + 15];
            int gr = 10 * b + lr;
            v = gr ? (acc + S2w[lr + 1]) : acc;
        }
        roffL[tid] = v;
    }
    __syncthreads();

    // per-sample: C = fl(prefix + roff); idx = (C - inc) % 512; lerp; amplitude
    #pragma unroll
    for (int i = 0; i < SPB / 512; ++i) {
        int tl = i * 512 + tid;
        size_t tg = base + tl;
        float C = pr[tl] + roffL[tl >> 4];
        float sub = C - increg[i];
        float idx = fmodf(sub, 512.0f);
        if (idx < 0.f) idx += 512.f;
        int li = (int)idx;
        float alpha = idx - (float)li;
        int hi = ((int)ceilf(idx)) & (WTLEN - 1);
        int fr = tl / BLKSZ;
        float wlo = mixrow[fr][li];
        float whi = mixrow[fr][hi];
        out[tg] = (wlo + alpha * (whi - wlo)) * amp[tg];
    }
}

extern "C" void kernel_launch(void* const* d_in, const int* in_sizes, int n_in,
                              void* d_out, int out_size, void* d_ws, size_t ws_size,
                              hipStream_t stream) {
    const float* pitch = (const float*)d_in[0];
    const float* amp   = (const float*)d_in[1];
    const float* wts   = (const float*)d_in[2];
    const float* att   = (const float*)d_in[3];

    int T      = in_sizes[0];        // 960000
    int frames = T / BLKSZ;          // 6000
    int nmain  = T / SPB;            // 375

    float* ws      = (float*)d_ws;
    float* wts_eff = ws;                     // 32768
    float* bs1     = ws + 32768;             // 3750 (pad 3840)
    float* bs2     = ws + 32768 + 3840;      // 235  (pad 256)
    float* S3      = ws + 32768 + 3840 + 256;// 235  (pad 256)
    float* wT      = ws + 32768 + 3840 + 512;// 375*1024 floats
    float* out     = (float*)d_out;

    k_front<<<LEAFB + WTSB + SMB, 256, 0, stream>>>(pitch, wts, att, bs1, bs2,
                                                    wts_eff, wT, T, frames);
    k_s3   <<<1, 256, 0, stream>>>(bs2, S3);
    k_main <<<nmain, 512, 0, stream>>>(pitch, amp, wts_eff, wT, bs1, S3, out, frames);
}